// Round 1
// baseline (718.085 us; speedup 1.0000x reference)
//
#include <hip/hip_runtime.h>
#include <cmath>
#include <vector>

#define B_ 64
#define NP 512   // N == M == 512, D == 2

constexpr float L2E  = 1.4426950408889634f;   // log2(e)
constexpr float LN2f = 0.6931471805599453f;

__device__ __forceinline__ float exp2_fast(float v) {
#if __has_builtin(__builtin_amdgcn_exp2f)
    return __builtin_amdgcn_exp2f(v);
#else
    return exp2f(v);
#endif
}
__device__ __forceinline__ float log2_fast(float v) {
#if __has_builtin(__builtin_amdgcn_logf)
    return __builtin_amdgcn_logf(v);
#else
    return log2f(v);
#endif
}

// Compute natural logs of the probability weights once.
__global__ __launch_bounds__(256) void logw_k(const float* __restrict__ a,
                                              const float* __restrict__ bb,
                                              float* __restrict__ alog,
                                              float* __restrict__ blog) {
    int i = blockIdx.x * 256 + threadIdx.x;   // grid covers exactly B_*NP
    alog[i] = logf(a[i]);
    blog[i] = logf(bb[i]);
}

// One softmin pass over both sides.
// mode 0: init   — h = olog            ; write val directly
// mode 1: iter   — h = olog + opot/eps ; write 0.5*(own_old + val)
// mode 2: final  — h = olog + opot/eps ; write val directly
// Grid: B_*8 blocks of 256 threads. q = blockIdx & 7: q<4 -> f-side rows (i over N,
// reduce over j in M, h from b_log/g), q>=4 -> g-side rows (j over M, reduce over i, h from a_log/f).
// Each pair of threads (tid, tid^1) shares one row, each half covers 256 j's.
__global__ __launch_bounds__(256) void softmin_k(
    const float* __restrict__ x, const float* __restrict__ y,
    const float* __restrict__ alog, const float* __restrict__ blog,
    const float* __restrict__ f_old, const float* __restrict__ g_old,
    float* __restrict__ f_new, float* __restrict__ g_new,
    float eps, int mode)
{
    __shared__ float sc[NP * 2];  // coords of the reduced-over side
    __shared__ float sh[NP];      // h * log2(e)
    const int b = blockIdx.x >> 3;
    const int q = blockIdx.x & 7;
    const bool gside = q >= 4;
    const int tid = threadIdx.x;
    const float inv_eps = 1.0f / eps;

    const float* ocoord = gside ? (x + b * NP * 2) : (y + b * NP * 2);
    const float* olog   = gside ? (alog + b * NP)  : (blog + b * NP);
    const float* opot   = gside ? (f_old + b * NP) : (g_old + b * NP);
    for (int t = tid; t < NP; t += 256) {
        sc[2 * t]     = ocoord[2 * t];
        sc[2 * t + 1] = ocoord[2 * t + 1];
        float h = olog[t];
        if (mode != 0) h = fmaf(opot[t], inv_eps, h);
        sh[t] = h * L2E;
    }
    __syncthreads();

    const int row  = ((q & 3) << 7) + (tid >> 1);
    const int half = tid & 1;
    const float* mcoord = gside ? (y + b * NP * 2) : (x + b * NP * 2);
    const float x0 = mcoord[2 * row];
    const float x1 = mcoord[2 * row + 1];
    // arg2(j) = L2E*(h_j - 0.5*dist2/eps) = sh[j] + dist2 * nie
    const float nie = -0.5f * inv_eps * L2E;

    float m = -INFINITY;
    float s = 0.0f;
    const int jbase = half * (NP / 2);
    for (int j0 = 0; j0 < NP / 2; j0 += 8) {
        float arg[8];
        #pragma unroll
        for (int u = 0; u < 8; ++u) {
            int j = jbase + j0 + u;
            float d0 = x0 - sc[2 * j];
            float d1 = x1 - sc[2 * j + 1];
            float c  = fmaf(d1, d1, d0 * d0);
            arg[u] = fmaf(c, nie, sh[j]);
        }
        float cm = fmaxf(fmaxf(fmaxf(arg[0], arg[1]), fmaxf(arg[2], arg[3])),
                         fmaxf(fmaxf(arg[4], arg[5]), fmaxf(arg[6], arg[7])));
        float mn = fmaxf(m, cm);
        s *= exp2_fast(m - mn);   // first chunk: exp2(-inf)=0, s stays 0
        #pragma unroll
        for (int u = 0; u < 8; ++u) s += exp2_fast(arg[u] - mn);
        m = mn;
    }

    // combine the two j-halves held by lane pair (tid, tid^1)
    float mo = __shfl_xor(m, 1);
    float so = __shfl_xor(s, 1);
    float mt = fmaxf(m, mo);
    float st = s * exp2_fast(m - mt) + so * exp2_fast(mo - mt);
    float val = -eps * (mt + log2_fast(st)) * LN2f;

    if (half == 0) {
        const float* own_old = gside ? (g_old + b * NP) : (f_old + b * NP);
        float* dst           = gside ? (g_new + b * NP) : (f_new + b * NP);
        if (mode == 1) val = 0.5f * (own_old[row] + val);
        dst[row] = val;
    }
}

// Per-batch weighted dot products -> partial[b] = w[b] * (<a,f_fin> + <b,g_fin>)
__global__ __launch_bounds__(256) void reduce1_k(
    const float* __restrict__ a, const float* __restrict__ bb,
    const float* __restrict__ ffin, const float* __restrict__ gfin,
    const float* __restrict__ w, float* __restrict__ partial)
{
    const int b = blockIdx.x, tid = threadIdx.x;
    float sum = 0.0f;
    for (int t = tid; t < 2 * NP; t += 256) {
        if (t < NP) sum += a[b * NP + t] * ffin[b * NP + t];
        else        sum += bb[b * NP + t - NP] * gfin[b * NP + t - NP];
    }
    #pragma unroll
    for (int o = 32; o > 0; o >>= 1) sum += __shfl_down(sum, o);
    __shared__ float red[4];
    if ((tid & 63) == 0) red[tid >> 6] = sum;
    __syncthreads();
    if (tid == 0) partial[b] = w[b] * (red[0] + red[1] + red[2] + red[3]);
}

__global__ void reduce2_k(const float* __restrict__ partial, float* __restrict__ out) {
    float v = partial[threadIdx.x];   // 64 threads, one wave
    #pragma unroll
    for (int o = 32; o > 0; o >>= 1) v += __shfl_down(v, o);
    if (threadIdx.x == 0) out[0] = v;
}

extern "C" void kernel_launch(void* const* d_in, const int* in_sizes, int n_in,
                              void* d_out, int out_size, void* d_ws, size_t ws_size,
                              hipStream_t stream) {
    const float* a  = (const float*)d_in[0];  // prob1   [B,N]
    const float* x  = (const float*)d_in[1];  // coord1  [B,N,2]
    const float* bb = (const float*)d_in[2];  // prob2   [B,M]
    const float* y  = (const float*)d_in[3];  // coord2  [B,M,2]
    const float* w  = (const float*)d_in[4];  // weights [B]
    float* out = (float*)d_out;

    float* ws = (float*)d_ws;
    const int NB = B_ * NP;
    float* alog = ws;
    float* blog = alog + NB;
    float* fA = blog + NB;
    float* gA = fA + NB;
    float* fB = gA + NB;
    float* gB = fB + NB;
    float* partial = gB + NB;  // 64 floats

    // eps schedule (matches geomloss/np.arange semantics, computed in double)
    std::vector<float> eps;
    {
        const double start = 2.0 * std::log(4.0);
        const double stop  = 2.0 * std::log(0.01);
        const double step  = 2.0 * std::log(0.9);
        eps.push_back(16.0f);                      // DIAMETER**P
        for (int k = 0;; ++k) {
            double v = start + (double)k * step;
            if (!(v > stop)) break;
            eps.push_back((float)std::exp(v));
        }
        eps.push_back((float)(0.01 * 0.01));       // BLUR**P
    }

    logw_k<<<(B_ * NP) / 256, 256, 0, stream>>>(a, bb, alog, blog);

    // init at coarsest temperature
    softmin_k<<<B_ * 8, 256, 0, stream>>>(x, y, alog, blog, fA, gA, fA, gA, eps[0], 0);

    float* fc = fA; float* gc = gA; float* fn = fB; float* gn = gB;
    for (size_t t = 0; t < eps.size(); ++t) {
        softmin_k<<<B_ * 8, 256, 0, stream>>>(x, y, alog, blog, fc, gc, fn, gn, eps[t], 1);
        std::swap(fc, fn); std::swap(gc, gn);
    }

    // final extrapolation at eps_last
    const float epsl = (float)(0.01 * 0.01);
    softmin_k<<<B_ * 8, 256, 0, stream>>>(x, y, alog, blog, fc, gc, fn, gn, epsl, 2);

    reduce1_k<<<B_, 256, 0, stream>>>(a, bb, fn, gn, w, partial);
    reduce2_k<<<1, 64, 0, stream>>>(partial, out);
}

// Round 2
// 564.722 us; speedup vs baseline: 1.2716x; 1.2716x over previous
//
#include <hip/hip_runtime.h>
#include <cmath>
#include <vector>

#define B_ 64
#define NP 512   // N == M == 512, D == 2

constexpr float L2E  = 1.4426950408889634f;   // log2(e)
constexpr float LN2f = 0.6931471805599453f;

__device__ __forceinline__ float exp2_fast(float v) {
#if __has_builtin(__builtin_amdgcn_exp2f)
    return __builtin_amdgcn_exp2f(v);
#else
    return exp2f(v);
#endif
}
__device__ __forceinline__ float log2_fast(float v) {
#if __has_builtin(__builtin_amdgcn_logf)
    return __builtin_amdgcn_logf(v);
#else
    return log2f(v);
#endif
}

// Precompute log2(e) * ln(prob) once.
__global__ __launch_bounds__(256) void logw_k(const float* __restrict__ a,
                                              const float* __restrict__ bb,
                                              float* __restrict__ alog,
                                              float* __restrict__ blog) {
    int i = blockIdx.x * 256 + threadIdx.x;   // grid covers exactly B_*NP
    alog[i] = L2E * logf(a[i]);
    blog[i] = L2E * logf(bb[i]);
}

// One softmin pass over both sides.
// mode 0: init   — h = olog            ; write val directly
// mode 1: iter   — h = olog + opot/eps ; write 0.5*(own_old + val)
// mode 2: final  — h = olog + opot/eps ; write val directly
//
// Grid: B_*8 blocks x 256 threads. q = blockIdx&7: q<4 -> f-side (rows over x,
// reduce over y), q>=4 -> g-side. rq = q&3 selects a 128-row quarter.
// Thread layout: oct = tid&7 owns j = oct (mod 8); rg = tid>>3 owns 4 rows.
// Each ds_read_b128 of {y0,y1,shp} serves 4 rows -> 4 B LDS per row-j.
__global__ __launch_bounds__(256) void softmin_k(
    const float* __restrict__ x, const float* __restrict__ y,
    const float* __restrict__ alog, const float* __restrict__ blog,
    const float* __restrict__ f_old, const float* __restrict__ g_old,
    float* __restrict__ f_new, float* __restrict__ g_new,
    float eps, int mode)
{
    __shared__ float4 sd[NP];   // {y0, y1, shp, pad} per reduced-over point
    const int b = blockIdx.x >> 3;
    const int q = blockIdx.x & 7;
    const bool gside = q >= 4;
    const int rq  = q & 3;
    const int tid = threadIdx.x;
    const float inv_eps = 1.0f / eps;
    const float ieL2E = inv_eps * L2E;          // coefficient of +x.y term
    const float nie   = -0.5f * ieL2E;          // coefficient of |.|^2 terms

    // ---- stage reduced-over side: coords + shp = h*log2e + nie*|y|^2 ----
    const float2* oc2   = (const float2*)(gside ? (x + b * NP * 2) : (y + b * NP * 2));
    const float*  olog  = gside ? (alog + b * NP)  : (blog + b * NP);
    const float*  opot  = gside ? (f_old + b * NP) : (g_old + b * NP);
    #pragma unroll
    for (int t0 = 0; t0 < NP; t0 += 256) {
        int t = t0 + tid;
        float2 c = oc2[t];
        float h2 = olog[t];                       // already *log2(e)
        if (mode != 0) h2 = fmaf(opot[t], ieL2E, h2);
        float shp = fmaf(nie, fmaf(c.y, c.y, c.x * c.x), h2);
        sd[t] = make_float4(c.x, c.y, shp, 0.0f);
    }
    __syncthreads();

    // ---- register-tiled online logsumexp ----
    const int oct = tid & 7;
    const int rowbase = rq * 128 + (tid >> 3) * 4;
    const float* mcoord = gside ? (y + b * NP * 2) : (x + b * NP * 2);
    const float4 rc01 = *(const float4*)(mcoord + rowbase * 2);       // rows 0,1
    const float4 rc23 = *(const float4*)(mcoord + rowbase * 2 + 4);   // rows 2,3
    float x0[4] = {rc01.x, rc01.z, rc23.x, rc23.z};
    float x1[4] = {rc01.y, rc01.w, rc23.y, rc23.w};
    float x0p[4], x1p[4], half_n2[4], m[4], s[4];
    #pragma unroll
    for (int r = 0; r < 4; ++r) {
        x0p[r] = x0[r] * ieL2E;
        x1p[r] = x1[r] * ieL2E;
        half_n2[r] = 0.5f * fmaf(x1[r], x1[r], x0[r] * x0[r]);
        m[r] = -INFINITY;
        s[r] = 0.0f;
    }

    #pragma unroll 1
    for (int k = 0; k < 8; ++k) {
        float4 cj[8];
        #pragma unroll
        for (int u = 0; u < 8; ++u) cj[u] = sd[64 * k + 8 * u + oct];
        #pragma unroll
        for (int r = 0; r < 4; ++r) {
            float arg[8];
            #pragma unroll
            for (int u = 0; u < 8; ++u)
                arg[u] = fmaf(x1p[r], cj[u].y, fmaf(x0p[r], cj[u].x, cj[u].z));
            float cm = fmaxf(fmaxf(fmaxf(arg[0], arg[1]), fmaxf(arg[2], arg[3])),
                             fmaxf(fmaxf(arg[4], arg[5]), fmaxf(arg[6], arg[7])));
            float mn = fmaxf(m[r], cm);
            s[r] *= exp2_fast(m[r] - mn);   // first chunk: exp2(-inf)=0
            #pragma unroll
            for (int u = 0; u < 8; ++u) s[r] += exp2_fast(arg[u] - mn);
            m[r] = mn;
        }
    }

    // ---- combine the 8 octants (lanes oct, oct^1, oct^2, oct^4) ----
    float val[4];
    #pragma unroll
    for (int r = 0; r < 4; ++r) {
        float mr = m[r], sr = s[r];
        #pragma unroll
        for (int d = 1; d <= 4; d <<= 1) {
            float mo = __shfl_xor(mr, d);
            float so = __shfl_xor(sr, d);
            float mt = fmaxf(mr, mo);
            sr = sr * exp2_fast(mr - mt) + so * exp2_fast(mo - mt);
            mr = mt;
        }
        val[r] = fmaf(-eps * LN2f, mr + log2_fast(sr), half_n2[r]);
    }

    if (oct == 0) {
        const float* own_old = gside ? (g_old + b * NP) : (f_old + b * NP);
        float*       dst     = gside ? (g_new + b * NP) : (f_new + b * NP);
        float4 o;
        if (mode == 1) {
            const float4 old4 = *(const float4*)(own_old + rowbase);
            o = make_float4(0.5f * (old4.x + val[0]), 0.5f * (old4.y + val[1]),
                            0.5f * (old4.z + val[2]), 0.5f * (old4.w + val[3]));
        } else {
            o = make_float4(val[0], val[1], val[2], val[3]);
        }
        *(float4*)(dst + rowbase) = o;
    }
}

// Per-batch weighted dot products -> partial[b] = w[b] * (<a,f_fin> + <b,g_fin>)
__global__ __launch_bounds__(256) void reduce1_k(
    const float* __restrict__ a, const float* __restrict__ bb,
    const float* __restrict__ ffin, const float* __restrict__ gfin,
    const float* __restrict__ w, float* __restrict__ partial)
{
    const int b = blockIdx.x, tid = threadIdx.x;
    float sum = 0.0f;
    for (int t = tid; t < 2 * NP; t += 256) {
        if (t < NP) sum += a[b * NP + t] * ffin[b * NP + t];
        else        sum += bb[b * NP + t - NP] * gfin[b * NP + t - NP];
    }
    #pragma unroll
    for (int o = 32; o > 0; o >>= 1) sum += __shfl_down(sum, o);
    __shared__ float red[4];
    if ((tid & 63) == 0) red[tid >> 6] = sum;
    __syncthreads();
    if (tid == 0) partial[b] = w[b] * (red[0] + red[1] + red[2] + red[3]);
}

__global__ void reduce2_k(const float* __restrict__ partial, float* __restrict__ out) {
    float v = partial[threadIdx.x];   // 64 threads, one wave
    #pragma unroll
    for (int o = 32; o > 0; o >>= 1) v += __shfl_down(v, o);
    if (threadIdx.x == 0) out[0] = v;
}

extern "C" void kernel_launch(void* const* d_in, const int* in_sizes, int n_in,
                              void* d_out, int out_size, void* d_ws, size_t ws_size,
                              hipStream_t stream) {
    const float* a  = (const float*)d_in[0];  // prob1   [B,N]
    const float* x  = (const float*)d_in[1];  // coord1  [B,N,2]
    const float* bb = (const float*)d_in[2];  // prob2   [B,M]
    const float* y  = (const float*)d_in[3];  // coord2  [B,M,2]
    const float* w  = (const float*)d_in[4];  // weights [B]
    float* out = (float*)d_out;

    float* ws = (float*)d_ws;
    const int NB = B_ * NP;
    float* alog = ws;
    float* blog = alog + NB;
    float* fA = blog + NB;
    float* gA = fA + NB;
    float* fB = gA + NB;
    float* gB = fB + NB;
    float* partial = gB + NB;  // 64 floats

    // eps schedule (geomloss epsilon_schedule semantics, computed in double)
    std::vector<float> eps;
    {
        const double start = 2.0 * std::log(4.0);
        const double stop  = 2.0 * std::log(0.01);
        const double step  = 2.0 * std::log(0.9);
        eps.push_back(16.0f);                      // DIAMETER**P
        for (int k = 0;; ++k) {
            double v = start + (double)k * step;
            if (!(v > stop)) break;
            eps.push_back((float)std::exp(v));
        }
        eps.push_back((float)(0.01 * 0.01));       // BLUR**P
    }

    logw_k<<<(B_ * NP) / 256, 256, 0, stream>>>(a, bb, alog, blog);

    // init at coarsest temperature
    softmin_k<<<B_ * 8, 256, 0, stream>>>(x, y, alog, blog, fA, gA, fA, gA, eps[0], 0);

    float* fc = fA; float* gc = gA; float* fn = fB; float* gn = gB;
    for (size_t t = 0; t < eps.size(); ++t) {
        softmin_k<<<B_ * 8, 256, 0, stream>>>(x, y, alog, blog, fc, gc, fn, gn, eps[t], 1);
        std::swap(fc, fn); std::swap(gc, gn);
    }

    // final extrapolation at eps_last
    const float epsl = (float)(0.01 * 0.01);
    softmin_k<<<B_ * 8, 256, 0, stream>>>(x, y, alog, blog, fc, gc, fn, gn, epsl, 2);

    reduce1_k<<<B_, 256, 0, stream>>>(a, bb, fn, gn, w, partial);
    reduce2_k<<<1, 64, 0, stream>>>(partial, out);
}